// Round 19
// baseline (66.687 us; speedup 1.0000x reference)
//
#include <hip/hip_runtime.h>

#define NN 32
#define MM 128
#define EE 256
#define DD 128
#define ELB 32   // e's per k_main block

typedef __attribute__((ext_vector_type(8))) short short8;
typedef __attribute__((ext_vector_type(4))) float f32x4;
typedef __attribute__((ext_vector_type(16))) float f32x16;

union U16x8 { uint4 u; short8 s; };

static __device__ __forceinline__ unsigned short f2bf(float f) {
  union { float f; unsigned u; } v; v.f = f;
  unsigned r = v.u + 0x7FFFu + ((v.u >> 16) & 1u);   // RNE
  return (unsigned short)(r >> 16);
}

// pack 8 f32 -> 8 bf16 via 4x v_cvt_pk_bf16_f32
static __device__ __forceinline__ U16x8 pk8(float4 a, float4 b) {
  U16x8 r;
  asm("v_cvt_pk_bf16_f32 %0, %1, %2" : "=v"(r.u.x) : "v"(a.x), "v"(a.y));
  asm("v_cvt_pk_bf16_f32 %0, %1, %2" : "=v"(r.u.y) : "v"(a.z), "v"(a.w));
  asm("v_cvt_pk_bf16_f32 %0, %1, %2" : "=v"(r.u.z) : "v"(b.x), "v"(b.y));
  asm("v_cvt_pk_bf16_f32 %0, %1, %2" : "=v"(r.u.w) : "v"(b.z), "v"(b.w));
  return r;
}

// ---- kernel 1: blocks 0..255 = prep wave-tasks (i = bid>>1, nh = bid&1, 1 wave);
//                256..319 = xt half-tiles; 320..447 = binc ----  (R17, unchanged)
__global__ __launch_bounds__(256, 1)
void k_pre(const float* __restrict__ X, const float* __restrict__ inc,
           const float* __restrict__ Wkk, const float* __restrict__ bkk,
           unsigned short* __restrict__ P1g, unsigned short* __restrict__ P0g,
           unsigned short* __restrict__ XTg, unsigned* __restrict__ bmap) {
  __shared__ float xs[64][129];
  const int bid = blockIdx.x;
  const int t = threadIdx.x;

  if (bid < 256) {  // ---- prep: one (i, n-half) per block, single wave ----
    if (t >= 64) return;
    const int i  = bid >> 1;
    const int nh = bid & 1;
    const int l  = t;
    const int lr = l & 15, lg = l >> 4;

    short8 a[4];
    {
      const int n = nh * 16 + lr;
      const float* xp = X + (n * MM + i) * DD + lg * 8;
#pragma unroll
      for (int k = 0; k < 4; ++k) {
        float4 v0 = *(const float4*)(xp + k * 32);
        float4 v1 = *(const float4*)(xp + k * 32 + 4);
        a[k] = pk8(v0, v1).s;
      }
    }
    f32x4 acc[8];
#pragma unroll
    for (int cf = 0; cf < 8; ++cf) acc[cf] = (f32x4){0.f, 0.f, 0.f, 0.f};
#pragma unroll
    for (int k = 0; k < 4; ++k) {
#pragma unroll
      for (int cf = 0; cf < 8; ++cf) {
        const int j = cf * 16 + lr;
        const float* wp = Wkk + (i * MM + j) * DD + k * 32 + lg * 8;
        float4 v0 = *(const float4*)(wp);
        float4 v1 = *(const float4*)(wp + 4);
        acc[cf] = __builtin_amdgcn_mfma_f32_16x16x32_bf16(a[k], pk8(v0, v1).s, acc[cf], 0, 0, 0);
      }
    }
    float bk[8];
#pragma unroll
    for (int cf = 0; cf < 8; ++cf) bk[cf] = bkk[i * MM + cf * 16 + lr];
#pragma unroll
    for (int r = 0; r < 4; ++r) {
      float v[8], m = -1e30f;
#pragma unroll
      for (int cf = 0; cf < 8; ++cf) { v[cf] = acc[cf][r] + bk[cf]; m = fmaxf(m, v[cf]); }
#pragma unroll
      for (int s = 1; s < 16; s <<= 1) m = fmaxf(m, __shfl_xor(m, s, 64));
      float sum = 0.f;
#pragma unroll
      for (int cf = 0; cf < 8; ++cf) { v[cf] = __expf(v[cf] - m); sum += v[cf]; }
#pragma unroll
      for (int s = 1; s < 16; s <<= 1) sum += __shfl_xor(sum, s, 64);
      const float inv = 1.f / sum;
      const int n = nh * 16 + lg * 4 + r;
      unsigned short* dst = P1g + (n * MM + i) * MM;
#pragma unroll
      for (int cf = 0; cf < 8; ++cf) dst[cf * 16 + lr] = f2bf(v[cf] * inv);
    }
    if (nh == 0) {  // P0 row i
      float v0 = bkk[i * MM + l], v1 = bkk[i * MM + 64 + l];
      float m = fmaxf(v0, v1);
#pragma unroll
      for (int s = 1; s < 64; s <<= 1) m = fmaxf(m, __shfl_xor(m, s, 64));
      v0 = __expf(v0 - m); v1 = __expf(v1 - m);
      float sum = v0 + v1;
#pragma unroll
      for (int s = 1; s < 64; s <<= 1) sum += __shfl_xor(sum, s, 64);
      const float inv = 1.f / sum;
      P0g[i * MM + l]      = f2bf(v0 * inv);
      P0g[i * MM + 64 + l] = f2bf(v1 * inv);
    }
  } else if (bid < 320) {  // ---- xt: XT[n][d][j] = bf16(X[n][j][d]), half-tile (64 j's) ----
    const int idx = bid - 256;
    const int n = idx >> 1, jh = idx & 1;
#pragma unroll
    for (int it = 0; it < 8; ++it) {
      int id2 = it * 256 + t;           // 0..2047 float4 tiles of the 64x128 half
      int j = id2 >> 5, dq = id2 & 31;
      float4 v = *(const float4*)(X + (n * MM + jh * 64 + j) * DD + dq * 4);
      xs[j][dq * 4 + 0] = v.x; xs[j][dq * 4 + 1] = v.y;
      xs[j][dq * 4 + 2] = v.z; xs[j][dq * 4 + 3] = v.w;
    }
    __syncthreads();
    const int d = t >> 1, half = t & 1;
    unsigned* dst = (unsigned*)XTg + (n * DD + d) * (MM / 2) + jh * 32 + half * 16;
#pragma unroll
    for (int wq = 0; wq < 16; ++wq) {
      int jl = half * 32 + wq * 2;
      unsigned u;
      asm("v_cvt_pk_bf16_f32 %0, %1, %2" : "=v"(u) : "v"(xs[jl][d]), "v"(xs[jl + 1][d]));
      dst[wq] = u;
    }
  } else {  // ---- binc: bitmap word q for 32 j's, e = t ----
    const int idx = bid - 320;
    const int n = idx >> 2, q = idx & 3;
    const int e = t;
    unsigned bm = 0;
#pragma unroll 4
    for (int j = 0; j < 32; ++j)
      if (inc[(n * MM + q * 32 + j) * EE + e] != 0.f) bm |= 1u << j;
    bmap[(n * EE + e) * 4 + q] = bm;
  }
}

// ---- kernel 2: main, 32x32x16 MFMA re-tile. 1024 blocks = 32n x 8eg x 4iq.
// Block owns 32 i x 128 d; 4 waves = 4 d-tiles of 32. Per wave per el: single acc tile,
// 8 chained MFMAs (K=128 in 8 steps of 16). Epilogue: in-lane w1-weighted relu reduce over
// the 16 C/D rows (col=lane&31=i, row=(reg&3)+8(reg>>2)+4(lane>>5)) + shfl_xor(32),
// then cross-wave d-combine via double-buffered LDS slot + 1 barrier/el. No atomics.
__global__ __launch_bounds__(256, 3)
void k_main(const unsigned short* __restrict__ P0g, const unsigned short* __restrict__ P1g,
            const unsigned short* __restrict__ XTg, const unsigned* __restrict__ bmap,
            const float* __restrict__ w1, const float* __restrict__ b1p,
            float* __restrict__ out) {
  __shared__ unsigned bitm[ELB][4];
  __shared__ alignas(16) unsigned short mrow[ELB][128];   // 8 KB
  __shared__ float comb[2][4][32];                         // 1 KB, double-buffered d-partials

  const int bid = blockIdx.x;
  const int n = bid & 31, eg = (bid >> 5) & 7, iq = bid >> 8;   // iq in 0..3
  const int t = threadIdx.x, w = t >> 6, l = t & 63;
  const int lc = l & 31, lh = l >> 5;       // col lane / k-half
  const int i_lane = iq * 32 + lc;          // this lane's P row / output-col index

  if (t < ELB)
    *(uint4*)&bitm[t][0] = *(const uint4*)(bmap + (n * EE + eg * ELB + t) * 4);

  // X fragments (A-operands): rows d = w*32 + lc, k = ks*16 + lh*8 + 0..7 -- pinned
  uint4 x[8];
  {
    const unsigned short* xb = XTg + n * DD * MM + (w * 32 + lc) * MM;
#pragma unroll
    for (int ks = 0; ks < 8; ++ks)
      x[ks] = *(const uint4*)(xb + ks * 16 + lh * 8);
  }
  // P fragments (B-operands): col i_lane, same k mapping -- pinned
  uint4 p0[8], p1[8];
  {
    const unsigned short* pb0 = P0g + i_lane * MM;
    const unsigned short* pb1 = P1g + n * MM * MM + i_lane * MM;
#pragma unroll
    for (int ks = 0; ks < 8; ++ks) {
      p0[ks] = *(const uint4*)(pb0 + ks * 16 + lh * 8);
      p1[ks] = *(const uint4*)(pb1 + ks * 16 + lh * 8);
    }
  }
  // w1 per C/D reg-row: row(r) = (r&3) + 8*(r>>2) + 4*lh, d = w*32 + row
  float w1reg[16];
#pragma unroll
  for (int r = 0; r < 16; ++r)
    w1reg[r] = w1[w * 32 + (r & 3) + 8 * (r >> 2) + 4 * lh];

  // PIN loop-invariants (compiler remat of these loads was the R4/R6 disaster)
#pragma unroll
  for (int ks = 0; ks < 8; ++ks) {
    asm volatile("" : "+v"(x[ks].x), "+v"(x[ks].y), "+v"(x[ks].z), "+v"(x[ks].w));
    asm volatile("" : "+v"(p0[ks].x), "+v"(p0[ks].y), "+v"(p0[ks].z), "+v"(p0[ks].w));
    asm volatile("" : "+v"(p1[ks].x), "+v"(p1[ks].y), "+v"(p1[ks].z), "+v"(p1[ks].w));
  }
#pragma unroll
  for (int r = 0; r < 16; ++r) asm volatile("" : "+v"(w1reg[r]));

  const float b1v = b1p[0];
  __syncthreads();

  {  // expand bitmap -> u16 AND-masks over contracted dim j (all 256 threads)
    int el = t >> 3, j0 = (t & 7) * 16;
    unsigned wd = bitm[el][j0 >> 5];
    int sh = j0 & 31;
    unsigned short* mp = &mrow[el][j0];
#pragma unroll
    for (int b = 0; b < 16; ++b) mp[b] = ((wd >> (sh + b)) & 1u) ? 0xFFFFu : 0u;
  }
  __syncthreads();

  float* outp = out + (n * EE + eg * ELB) * MM + iq * 32;
  const char* mbase = (const char*)&mrow[0][0] + lh * 16;

#pragma unroll 1
  for (int el = 0; el < ELB; ++el) {
    const bool sel = ((bitm[el][iq] >> lc) & 1u) != 0u;

    f32x16 acc = {0.f,0.f,0.f,0.f,0.f,0.f,0.f,0.f,0.f,0.f,0.f,0.f,0.f,0.f,0.f,0.f};
    __builtin_amdgcn_s_setprio(1);
#pragma unroll
    for (int ks = 0; ks < 8; ++ks) {
      uint4 mm = *(const uint4*)(mbase + el * 256 + ks * 32);
      U16x8 pv;
      pv.u.x = (sel ? p1[ks].x : p0[ks].x) & mm.x;
      pv.u.y = (sel ? p1[ks].y : p0[ks].y) & mm.y;
      pv.u.z = (sel ? p1[ks].z : p0[ks].z) & mm.z;
      pv.u.w = (sel ? p1[ks].w : p0[ks].w) & mm.w;
      U16x8 xv; xv.u = x[ks];
      acc = __builtin_amdgcn_mfma_f32_32x32x16_bf16(xv.s, pv.s, acc, 0, 0, 0);
    }
    __builtin_amdgcn_s_setprio(0);

    // in-lane pooled partial over this wave's 16 d-rows (4 parallel fma chains)
    float s0 = fmaxf(acc[0], 0.f) * w1reg[0];
    float s1 = fmaxf(acc[1], 0.f) * w1reg[1];
    float s2 = fmaxf(acc[2], 0.f) * w1reg[2];
    float s3 = fmaxf(acc[3], 0.f) * w1reg[3];
#pragma unroll
    for (int r = 4; r < 16; r += 4) {
      s0 += fmaxf(acc[r + 0], 0.f) * w1reg[r + 0];
      s1 += fmaxf(acc[r + 1], 0.f) * w1reg[r + 1];
      s2 += fmaxf(acc[r + 2], 0.f) * w1reg[r + 2];
      s3 += fmaxf(acc[r + 3], 0.f) * w1reg[r + 3];
    }
    float pooled = (s0 + s1) + (s2 + s3);
    pooled += __shfl_xor(pooled, 32, 64);     // join the two lh row-sets -> full 32-d tile

    if (l < 32) comb[el & 1][w][l] = pooled;  // publish this wave's d-tile partial
    __syncthreads();
    if (w == (el & 3) && l < 32) {            // rotating finalizer sums 4 d-tiles
      float s = ((comb[el & 1][0][l] + comb[el & 1][1][l]) +
                 (comb[el & 1][2][l] + comb[el & 1][3][l])) + b1v;
      outp[el * MM + l] = s;
    }
  }
}

extern "C" void kernel_launch(void* const* d_in, const int* in_sizes, int n_in,
                              void* d_out, int out_size, void* d_ws, size_t ws_size,
                              hipStream_t stream) {
  const float* X   = (const float*)d_in[0];
  const float* inc = (const float*)d_in[1];
  const float* Wkk = (const float*)d_in[2];
  const float* bkk = (const float*)d_in[3];
  const float* w1  = (const float*)d_in[4];
  const float* b1  = (const float*)d_in[5];
  float* out = (float*)d_out;

  unsigned short* P1g = (unsigned short*)d_ws;          // 32*128*128 u16 = 1 MB
  unsigned short* XTg = P1g + NN * MM * DD;             // 1 MB
  unsigned short* P0g = XTg + NN * MM * DD;             // 32 KB
  unsigned* bmap = (unsigned*)(P0g + MM * MM);          // 32*256*4 u32 = 128 KB

  hipLaunchKernelGGL(k_pre,  dim3(448),  dim3(256), 0, stream, X, inc, Wkk, bkk, P1g, P0g, XTg, bmap);
  hipLaunchKernelGGL(k_main, dim3(1024), dim3(256), 0, stream, P0g, P1g, XTg, bmap, w1, b1, out);
}

// Round 20
// 49.451 us; speedup vs baseline: 1.3485x; 1.3485x over previous
//
#include <hip/hip_runtime.h>

#define NN 32
#define MM 128
#define EE 256
#define DD 128
#define ELB 32   // e's per k_main block

typedef __attribute__((ext_vector_type(8))) short short8;
typedef __attribute__((ext_vector_type(4))) float f32x4;

union U16x8 { uint4 u; short8 s; };

static __device__ __forceinline__ unsigned short f2bf(float f) {
  union { float f; unsigned u; } v; v.f = f;
  unsigned r = v.u + 0x7FFFu + ((v.u >> 16) & 1u);   // RNE
  return (unsigned short)(r >> 16);
}

// pack 8 f32 -> 8 bf16 via 4x v_cvt_pk_bf16_f32
static __device__ __forceinline__ U16x8 pk8(float4 a, float4 b) {
  U16x8 r;
  asm("v_cvt_pk_bf16_f32 %0, %1, %2" : "=v"(r.u.x) : "v"(a.x), "v"(a.y));
  asm("v_cvt_pk_bf16_f32 %0, %1, %2" : "=v"(r.u.y) : "v"(a.z), "v"(a.w));
  asm("v_cvt_pk_bf16_f32 %0, %1, %2" : "=v"(r.u.z) : "v"(b.x), "v"(b.y));
  asm("v_cvt_pk_bf16_f32 %0, %1, %2" : "=v"(r.u.w) : "v"(b.z), "v"(b.w));
  return r;
}

// ---- kernel 1: blocks 0..255 = prep wave-tasks (i = bid>>1, nh = bid&1, 1 wave);
//                256..319 = xt half-tiles; 320..447 = binc ----
__global__ __launch_bounds__(256, 1)
void k_pre(const float* __restrict__ X, const float* __restrict__ inc,
           const float* __restrict__ Wkk, const float* __restrict__ bkk,
           unsigned short* __restrict__ P1g, unsigned short* __restrict__ P0g,
           unsigned short* __restrict__ XTg, unsigned* __restrict__ bmap) {
  __shared__ float xs[64][129];
  const int bid = blockIdx.x;
  const int t = threadIdx.x;

  if (bid < 256) {  // ---- prep: one (i, n-half) per block, single wave ----
    if (t >= 64) return;
    const int i  = bid >> 1;
    const int nh = bid & 1;
    const int l  = t;
    const int lr = l & 15, lg = l >> 4;

    short8 a[4];
    {
      const int n = nh * 16 + lr;
      const float* xp = X + (n * MM + i) * DD + lg * 8;
#pragma unroll
      for (int k = 0; k < 4; ++k) {
        float4 v0 = *(const float4*)(xp + k * 32);
        float4 v1 = *(const float4*)(xp + k * 32 + 4);
        a[k] = pk8(v0, v1).s;
      }
    }
    f32x4 acc[8];
#pragma unroll
    for (int cf = 0; cf < 8; ++cf) acc[cf] = (f32x4){0.f, 0.f, 0.f, 0.f};
#pragma unroll
    for (int k = 0; k < 4; ++k) {
#pragma unroll
      for (int cf = 0; cf < 8; ++cf) {
        const int j = cf * 16 + lr;
        const float* wp = Wkk + (i * MM + j) * DD + k * 32 + lg * 8;
        float4 v0 = *(const float4*)(wp);
        float4 v1 = *(const float4*)(wp + 4);
        acc[cf] = __builtin_amdgcn_mfma_f32_16x16x32_bf16(a[k], pk8(v0, v1).s, acc[cf], 0, 0, 0);
      }
    }
    float bk[8];
#pragma unroll
    for (int cf = 0; cf < 8; ++cf) bk[cf] = bkk[i * MM + cf * 16 + lr];
#pragma unroll
    for (int r = 0; r < 4; ++r) {
      float v[8], m = -1e30f;
#pragma unroll
      for (int cf = 0; cf < 8; ++cf) { v[cf] = acc[cf][r] + bk[cf]; m = fmaxf(m, v[cf]); }
#pragma unroll
      for (int s = 1; s < 16; s <<= 1) m = fmaxf(m, __shfl_xor(m, s, 64));
      float sum = 0.f;
#pragma unroll
      for (int cf = 0; cf < 8; ++cf) { v[cf] = __expf(v[cf] - m); sum += v[cf]; }
#pragma unroll
      for (int s = 1; s < 16; s <<= 1) sum += __shfl_xor(sum, s, 64);
      const float inv = 1.f / sum;
      const int n = nh * 16 + lg * 4 + r;
      unsigned short* dst = P1g + (n * MM + i) * MM;
#pragma unroll
      for (int cf = 0; cf < 8; ++cf) dst[cf * 16 + lr] = f2bf(v[cf] * inv);
    }
    if (nh == 0) {  // P0 row i
      float v0 = bkk[i * MM + l], v1 = bkk[i * MM + 64 + l];
      float m = fmaxf(v0, v1);
#pragma unroll
      for (int s = 1; s < 64; s <<= 1) m = fmaxf(m, __shfl_xor(m, s, 64));
      v0 = __expf(v0 - m); v1 = __expf(v1 - m);
      float sum = v0 + v1;
#pragma unroll
      for (int s = 1; s < 64; s <<= 1) sum += __shfl_xor(sum, s, 64);
      const float inv = 1.f / sum;
      P0g[i * MM + l]      = f2bf(v0 * inv);
      P0g[i * MM + 64 + l] = f2bf(v1 * inv);
    }
  } else if (bid < 320) {  // ---- xt: XT[n][d][j] = bf16(X[n][j][d]), half-tile (64 j's) ----
    const int idx = bid - 256;
    const int n = idx >> 1, jh = idx & 1;
#pragma unroll
    for (int it = 0; it < 8; ++it) {
      int id2 = it * 256 + t;           // 0..2047 float4 tiles of the 64x128 half
      int j = id2 >> 5, dq = id2 & 31;
      float4 v = *(const float4*)(X + (n * MM + jh * 64 + j) * DD + dq * 4);
      xs[j][dq * 4 + 0] = v.x; xs[j][dq * 4 + 1] = v.y;
      xs[j][dq * 4 + 2] = v.z; xs[j][dq * 4 + 3] = v.w;
    }
    __syncthreads();
    const int d = t >> 1, half = t & 1;
    unsigned* dst = (unsigned*)XTg + (n * DD + d) * (MM / 2) + jh * 32 + half * 16;
#pragma unroll
    for (int wq = 0; wq < 16; ++wq) {
      int jl = half * 32 + wq * 2;
      unsigned u;
      asm("v_cvt_pk_bf16_f32 %0, %1, %2" : "=v"(u) : "v"(xs[jl][d]), "v"(xs[jl + 1][d]));
      dst[wq] = u;
    }
  } else {  // ---- binc: bitmap word q for 32 j's, e = t ----
    const int idx = bid - 320;
    const int n = idx >> 2, q = idx & 3;
    const int e = t;
    unsigned bm = 0;
#pragma unroll 4
    for (int j = 0; j < 32; ++j)
      if (inc[(n * MM + q * 32 + j) * EE + e] != 0.f) bm |= 1u << j;
    bmap[(n * EE + e) * 4 + q] = bm;
  }
}

// ---- kernel 2: main (R14-benched version, best measured: 40.5us, VGPR 108, no spill).
// 512 blocks = 32n x 8eg x 2rh. T^T = XT * P^T, X pinned in regs; per-el bitm/mrow reads;
// dual a0v/a1v chains per p; single eA epilogue chain; setprio around main MFMAs.
__global__ __launch_bounds__(256, 2)
void k_main(const unsigned short* __restrict__ P0g, const unsigned short* __restrict__ P1g,
            const unsigned short* __restrict__ XTg, const unsigned* __restrict__ bmap,
            const float* __restrict__ w1, const float* __restrict__ b1p,
            float* __restrict__ out) {
  __shared__ unsigned bitm[ELB][4];
  __shared__ alignas(16) unsigned short mrow[ELB][128];     // 8 KB

  const int bid = blockIdx.x;
  const int n = bid & 31, eg = (bid >> 5) & 7, rh = bid >> 8;
  const int t = threadIdx.x, w = t >> 6, l = t & 63, lr = l & 15, lg = l >> 4;
  const int i_lane = rh * 64 + w * 16 + lr;   // this lane's P row / output-col index

  if (t < ELB)
    *(uint4*)&bitm[t][0] = *(const uint4*)(bmap + (n * EE + eg * ELB + t) * 4);

  // X fragments (A-operands, el-invariant): rows d = cf*16+lr -- loaded ONCE from global, pinned
  uint4 x[8][4];
  {
    const unsigned short* xb = XTg + n * DD * MM;
#pragma unroll
    for (int cf = 0; cf < 8; ++cf)
#pragma unroll
      for (int k = 0; k < 4; ++k)
        x[cf][k] = *(const uint4*)(xb + (cf * 16 + lr) * MM + k * 32 + lg * 8);
  }
  // P fragments (B-operands): row i_lane, k-slices -- loaded ONCE, pinned
  uint4 p0[4], p1[4];
  {
    const unsigned short* pb0 = P0g + i_lane * MM;
    const unsigned short* pb1 = P1g + n * MM * MM + i_lane * MM;
#pragma unroll
    for (int k = 0; k < 4; ++k) {
      p0[k] = *(const uint4*)(pb0 + k * 32 + lg * 8);
      p1[k] = *(const uint4*)(pb1 + k * 32 + lg * 8);
    }
  }
  // w1 B-fragments, packed per cf-pair for the K=32 epilogue contraction
  U16x8 w1u[4];
#pragma unroll
  for (int p = 0; p < 4; ++p) {
    float4 a = *(const float4*)(w1 + (2 * p) * 16 + lg * 4);
    float4 b = *(const float4*)(w1 + (2 * p + 1) * 16 + lg * 4);
    w1u[p] = pk8(a, b);
  }
  // PIN all loop-invariants: read-write asm forbids sinking/remat of the loads.
#pragma unroll
  for (int cf = 0; cf < 8; ++cf) {
#pragma unroll
    for (int k = 0; k < 4; ++k)
      asm volatile("" : "+v"(x[cf][k].x), "+v"(x[cf][k].y), "+v"(x[cf][k].z), "+v"(x[cf][k].w));
  }
#pragma unroll
  for (int k = 0; k < 4; ++k) {
    asm volatile("" : "+v"(p0[k].x), "+v"(p0[k].y), "+v"(p0[k].z), "+v"(p0[k].w));
    asm volatile("" : "+v"(p1[k].x), "+v"(p1[k].y), "+v"(p1[k].z), "+v"(p1[k].w));
    asm volatile("" : "+v"(w1u[k].u.x), "+v"(w1u[k].u.y), "+v"(w1u[k].u.z), "+v"(w1u[k].u.w));
  }
  const float b1v = b1p[0];
  const int selsh = (w & 1) * 16 + lr;
  const int selwd = rh * 2 + (w >> 1);
  __syncthreads();

  {  // expand bitmap -> u16 AND-masks over contracted dim j (all 256 threads)
    int el = t >> 3, j0 = (t & 7) * 16;
    unsigned wd = bitm[el][j0 >> 5];
    int sh = j0 & 31;
    unsigned short* mp = &mrow[el][j0];
#pragma unroll
    for (int b = 0; b < 16; ++b) mp[b] = ((wd >> (sh + b)) & 1u) ? 0xFFFFu : 0u;
  }
  __syncthreads();

  float* outp = out + (n * EE + eg * ELB) * MM + rh * 64 + w * 16 + lg * 4;
  const char* mbase = (const char*)&mrow[0][0] + lg * 16;

#pragma unroll 1
  for (int el = 0; el < ELB; ++el) {
    const bool sel = ((bitm[el][selwd] >> selsh) & 1u) != 0u;

    // select+mask P once per e (k-slices)
    U16x8 pv[4];
#pragma unroll
    for (int k = 0; k < 4; ++k) {
      uint4 mm = *(const uint4*)(mbase + el * 256 + k * 64);
      pv[k].u.x = (sel ? p1[k].x : p0[k].x) & mm.x;
      pv[k].u.y = (sel ? p1[k].y : p0[k].y) & mm.y;
      pv[k].u.z = (sel ? p1[k].z : p0[k].z) & mm.z;
      pv[k].u.w = (sel ? p1[k].w : p0[k].w) & mm.w;
    }

    f32x4 eA = (f32x4){b1v, b1v, b1v, b1v};
#pragma unroll
    for (int p = 0; p < 4; ++p) {
      __builtin_amdgcn_s_setprio(1);
      f32x4 a0v = (f32x4){0.f,0.f,0.f,0.f}, a1v = (f32x4){0.f,0.f,0.f,0.f};
#pragma unroll
      for (int k = 0; k < 4; ++k) {
        U16x8 xv0; xv0.u = x[2*p][k];
        U16x8 xv1; xv1.u = x[2*p+1][k];
        a0v = __builtin_amdgcn_mfma_f32_16x16x32_bf16(xv0.s, pv[k].s, a0v, 0, 0, 0);
        a1v = __builtin_amdgcn_mfma_f32_16x16x32_bf16(xv1.s, pv[k].s, a1v, 0, 0, 0);
      }
      __builtin_amdgcn_s_setprio(0);
      float f0 = fmaxf(a0v[0],0.f), f1 = fmaxf(a0v[1],0.f), f2 = fmaxf(a0v[2],0.f), f3 = fmaxf(a0v[3],0.f);
      float g0 = fmaxf(a1v[0],0.f), g1 = fmaxf(a1v[1],0.f), g2 = fmaxf(a1v[2],0.f), g3 = fmaxf(a1v[3],0.f);
      unsigned u0,u1,u2,u3;
      asm("v_cvt_pk_bf16_f32 %0, %1, %2" : "=v"(u0) : "v"(f0), "v"(f1));
      asm("v_cvt_pk_bf16_f32 %0, %1, %2" : "=v"(u1) : "v"(f2), "v"(f3));
      asm("v_cvt_pk_bf16_f32 %0, %1, %2" : "=v"(u2) : "v"(g0), "v"(g1));
      asm("v_cvt_pk_bf16_f32 %0, %1, %2" : "=v"(u3) : "v"(g2), "v"(g3));
      U16x8 uu; uu.u.x = u0; uu.u.y = u1; uu.u.z = u2; uu.u.w = u3;
      eA = __builtin_amdgcn_mfma_f32_16x16x32_bf16(uu.s, w1u[p].s, eA, 0, 0, 0);
    }

    if (lr == 0) *(float4*)(outp + el * MM) = *(float4*)&eA;
  }
}

extern "C" void kernel_launch(void* const* d_in, const int* in_sizes, int n_in,
                              void* d_out, int out_size, void* d_ws, size_t ws_size,
                              hipStream_t stream) {
  const float* X   = (const float*)d_in[0];
  const float* inc = (const float*)d_in[1];
  const float* Wkk = (const float*)d_in[2];
  const float* bkk = (const float*)d_in[3];
  const float* w1  = (const float*)d_in[4];
  const float* b1  = (const float*)d_in[5];
  float* out = (float*)d_out;

  unsigned short* P1g = (unsigned short*)d_ws;          // 32*128*128 u16 = 1 MB
  unsigned short* XTg = P1g + NN * MM * DD;             // 1 MB
  unsigned short* P0g = XTg + NN * MM * DD;             // 32 KB
  unsigned* bmap = (unsigned*)(P0g + MM * MM);          // 32*256*4 u32 = 128 KB

  hipLaunchKernelGGL(k_pre,  dim3(448), dim3(256), 0, stream, X, inc, Wkk, bkk, P1g, P0g, XTg, bmap);
  hipLaunchKernelGGL(k_main, dim3(512), dim3(256), 0, stream, P0g, P1g, XTg, bmap, w1, b1, out);
}